// Round 8
// baseline (361.277 us; speedup 1.0000x reference)
//
#include <hip/hip_runtime.h>
#include <stdint.h>

#define GSZ 60
#define KNB 13
#define NPT 512

typedef __attribute__((ext_vector_type(4))) float f32x4;
typedef __attribute__((ext_vector_type(8))) short s16x8;
typedef __attribute__((ext_vector_type(8))) ushort u16x8;

__device__ __forceinline__ ushort f2bf(float f) {
  union { float f; unsigned u; } v; v.f = f;
  unsigned r = v.u + 0x7fffu + ((v.u >> 16) & 1u);
  return (ushort)(r >> 16);
}
__device__ __forceinline__ float bf2f(ushort h) {
  union { unsigned u; float f; } v; v.u = ((unsigned)h) << 16;
  return v.f;
}

// async global->LDS, 16B per lane; dst wave-uniform (HW adds lane*16)
__device__ __forceinline__ void gload_lds16(const void* gsrc, void* ldst) {
  __builtin_amdgcn_global_load_lds(
      (const __attribute__((address_space(1))) uint32_t*)gsrc,
      (__attribute__((address_space(3))) uint32_t*)ldst, 16, 0, 0);
}

// feats [N][32][G] fp32 -> X0 [61][N][32] bf16 (panel 60 = zeros)
__global__ __launch_bounds__(256) void prep_feats_k(const float* __restrict__ feats,
                                                    ushort* __restrict__ X0) {
  int idx = blockIdx.x * 256 + threadIdx.x;
  if (idx >= 61 * NPT * 32) return;
  int c = idx & 31;
  int t = idx >> 5;
  int n = t % NPT;
  int g = t / NPT;
  X0[idx] = (g < GSZ) ? f2bf(feats[(n * 32 + c) * GSZ + g]) : (ushort)0;
}

// W [O][C][13] fp32 -> Wb [OPAD][KPAD] bf16
__global__ __launch_bounds__(256) void prep_wb_k(const float* __restrict__ W,
                                                 ushort* __restrict__ Wb,
                                                 int O, int OPAD, int C, int KPAD) {
  int idx = blockIdx.x * 256 + threadIdx.x;
  if (idx >= OPAD * KPAD) return;
  int o = idx / KPAD;
  int kk = idx - o * KPAD;
  int k = kk / C;
  int c = kk - k * C;
  Wb[idx] = (o < O && k < KNB) ? f2bf(W[(o * C + c) * KNB + k]) : (ushort)0;
}

// ---------------- 4-wave 128xBN dbuf kernel (L1, L4 split-K) — proven ----------------
template <int CIN, int KTOT, int OPAD, int OREAL, int BN, int MODE, bool RELU>
__global__ __launch_bounds__(256) void comb_gemm(
    const ushort* __restrict__ Xin, const ushort* __restrict__ Wb,
    const float* __restrict__ bias, const int* __restrict__ nei,
    ushort* __restrict__ Xout, float* __restrict__ Eq,
    const float* __restrict__ feats, int qb, int qe) {
  constexpr int BM = 128;
  constexpr int BK = 64;
  constexpr int TO = OPAD / BN;
  constexpr int TN = NPT / BM;
  constexpr int WN = BN / 2;
  constexpr int N_REP = WN / 16;
  constexpr int M_REP = 4;
  constexpr int CSH = (CIN == 32) ? 5 : (CIN == 256) ? 8 : 9;
  static_assert(CIN == (1 << CSH), "CIN pow2");

  __shared__ ushort smA[2][BM * BK];
  __shared__ ushort smB[2][BN * BK];
  __shared__ int nei_sh[16];

  const int nwg = TO * TN * GSZ;
  const int cpx = nwg >> 3;
  const int bid = blockIdx.x;
  const int idx = (bid & 7) * cpx + (bid >> 3);
  const int g = idx / (TO * TN);
  const int rem = idx - g * (TO * TN);
  const int nt = rem / TO;
  const int ot = rem - nt * TO;
  const int n0 = nt * BM;
  const int o0 = ot * BN;

  const int t = threadIdx.x;
  if (t < 14) nei_sh[t] = (t < KNB) ? nei[g * KNB + t] : GSZ;
  __syncthreads();

  const int w = t >> 6;
  const int l = t & 63;
  const int lrow = l & 15;
  const int lkg = l >> 4;
  const int wr = w >> 1;
  const int wc = w & 1;
  const int srow_w = w * 8;
  const int sr = l >> 3;
  const int slot = l & 7;

  int laneA[BM / 32], laneB[BN / 32], swz[BM / 32];
#pragma unroll
  for (int j = 0; j < BM / 32; ++j) {
    const int r = j * 32 + srow_w + sr;
    swz[j] = (slot ^ (r & 7)) << 3;
    laneA[j] = ((n0 + r) << CSH) + swz[j];
  }
#pragma unroll
  for (int j = 0; j < BN / 32; ++j) {
    const int r = j * 32 + srow_w + sr;
    laneB[j] = (o0 + r) * KTOT + ((slot ^ (r & 7)) << 3);
  }

  auto stage = [&](int buf, int q) {
    const int c0 = q * BK;
    if constexpr (CIN >= 64) {
      const int pbase = nei_sh[c0 >> CSH] * (NPT << CSH) + (c0 & (CIN - 1));
#pragma unroll
      for (int j = 0; j < BM / 32; ++j)
        gload_lds16(Xin + pbase + laneA[j], &smA[buf][(j * 32 + srow_w) * BK]);
    } else {
#pragma unroll
      for (int j = 0; j < BM / 32; ++j) {
        const int r = j * 32 + srow_w + sr;
        const int kk = c0 + swz[j];
        const int nbr = kk >> CSH;
        const int cc = kk & (CIN - 1);
        gload_lds16(Xin + ((nei_sh[nbr] * NPT + n0 + r) << CSH) + cc,
                    &smA[buf][(j * 32 + srow_w) * BK]);
      }
    }
#pragma unroll
    for (int j = 0; j < BN / 32; ++j)
      gload_lds16(Wb + laneB[j] + c0, &smB[buf][(j * 32 + srow_w) * BK]);
  };

  f32x4 acc[M_REP][N_REP] = {};

  stage(0, qb);
  asm volatile("s_waitcnt vmcnt(0)" ::: "memory");
  __builtin_amdgcn_s_barrier();

  int cur = 0;
#pragma unroll 1
  for (int q = qb; q < qe; ++q) {
    if (q + 1 < qe) stage(cur ^ 1, q + 1);
#pragma unroll
    for (int ks = 0; ks < 2; ++ks) {
      const int cb = ks * 4 + lkg;
      s16x8 bf[N_REP];
#pragma unroll
      for (int n = 0; n < N_REP; ++n) {
        const int r = wc * WN + n * 16 + lrow;
        bf[n] = *(const s16x8*)&smB[cur][r * BK + ((cb ^ (r & 7)) << 3)];
      }
#pragma unroll
      for (int m = 0; m < M_REP; ++m) {
        const int r = wr * 64 + m * 16 + lrow;
        s16x8 af = *(const s16x8*)&smA[cur][r * BK + ((cb ^ (r & 7)) << 3)];
#pragma unroll
        for (int n = 0; n < N_REP; ++n)
          acc[m][n] = __builtin_amdgcn_mfma_f32_16x16x32_bf16(af, bf[n], acc[m][n], 0, 0, 0);
      }
    }
    asm volatile("s_waitcnt vmcnt(0)" ::: "memory");
    __builtin_amdgcn_s_barrier();
    cur ^= 1;
  }

#pragma unroll
  for (int m = 0; m < M_REP; ++m) {
#pragma unroll
    for (int n = 0; n < N_REP; ++n) {
      const int oc = o0 + wc * WN + n * 16 + lrow;
      float bv;
      if (MODE == 2)
        bv = (oc < OREAL && feats) ? bias[oc] : 0.f;
      else
        bv = bias[oc];
#pragma unroll
      for (int r = 0; r < 4; ++r) {
        const int row = n0 + wr * 64 + m * 16 + lkg * 4 + r;
        float v = acc[m][n][r] + bv;
        if (MODE == 0) {
          if (RELU) v = v > 0.f ? v : 0.f;
          Xout[((size_t)g * NPT + row) * OPAD + oc] = f2bf(v);
        } else if (MODE == 1) {
          const size_t ix = ((size_t)g * NPT + row) * OPAD + oc;
          Xout[ix] = f2bf(bf2f(Xout[ix]) + v);
        } else {
          const float add = (oc < OREAL && feats) ? feats[((size_t)row * 32 + oc) * GSZ + g] : 0.f;
          Eq[((size_t)g * NPT + row) * 64 + oc] = v + add;
        }
      }
    }
  }
}

// ---------- 8-phase 256x256 kernel (m201 template, proven quadrant) ----------
// 8 waves (2M x 4N), per-wave 128x64 out. LDS [2dbuf][2 khalf][256][32] per matrix.
// Phase: {ds_read 8|4 b128, stage 1 half-tile (2 gload), barrier, prio1, 16 MFMA,
// prio0, [vmcnt(8) at phases 2&4], barrier}. 2-tile stage lookahead, peeled tail.
// MODE 0: bf16(acc+bias) (+RELU). MODE 3: raw bf16 partial -> Xout + kp*part.
template <int CIN, int KTOT, int OPAD, int MODE, bool RELU, int SPLITK>
__global__ __launch_bounds__(512, 2) void comb8p256(
    const ushort* __restrict__ Xin, const ushort* __restrict__ Wb,
    const float* __restrict__ bias, const int* __restrict__ nei,
    ushort* __restrict__ Xout) {
  constexpr int BM = 256, BN = 256;
  constexpr int NTL = KTOT / 64 / SPLITK;  // 52
  constexpr int TO = OPAD / BN;
  constexpr int TN = NPT / BM;  // 2
  constexpr int CSH = (CIN == 256) ? 8 : 9;
  static_assert(CIN == (1 << CSH), "CIN pow2");

  __shared__ ushort smA[2][2][BM * 32];  // 64 KB
  __shared__ ushort smB[2][2][BN * 32];  // 64 KB
  __shared__ int nei_sh[16];

  const int nparts = TO * TN * GSZ;
  const int nwg = nparts * SPLITK;  // 240
  const int cpx = nwg >> 3;
  const int bid = blockIdx.x;
  const int idxa = (bid & 7) * cpx + (bid >> 3);
  const int kp = idxa / nparts;
  const int sub = idxa - kp * nparts;
  const int g = sub / (TO * TN);
  const int rem = sub - g * (TO * TN);
  const int nt = rem / TO;
  const int ot = rem - nt * TO;
  const int n0 = nt * BM;
  const int o0 = ot * BN;
  const int qb = kp * NTL;

  const int t = threadIdx.x;
  if (t < 14) nei_sh[t] = (t < KNB) ? nei[g * KNB + t] : GSZ;
  __syncthreads();

  const int w = t >> 6;
  const int l = t & 63;
  const int lrow = l & 15;
  const int lkg = l >> 4;  // 16B slot within 32-k half
  const int wr = w >> 2;   // 0..1
  const int wc = w & 3;    // 0..3

  // staging: instr j covers rows w*32+j*16+(l>>2), 4 lanes/row (64B rows)
  int laneA[2], laneB[2];
#pragma unroll
  for (int j = 0; j < 2; ++j) {
    const int r = w * 32 + j * 16 + (l >> 2);
    const int s = (l & 3) ^ ((r >> 1) & 3);  // inverse-swizzled global slot
    laneA[j] = ((n0 + r) << CSH) + s * 8;
    laneB[j] = (o0 + r) * KTOT + s * 8;
  }

  auto stageA = [&](int buf, int h, int tg) {
    const int k0 = tg * 64 + h * 32;
    const int pbase = nei_sh[k0 >> CSH] * (NPT << CSH) + (k0 & (CIN - 1));
#pragma unroll
    for (int j = 0; j < 2; ++j)
      gload_lds16(Xin + pbase + laneA[j], &smA[buf][h][(w * 32 + j * 16) * 32]);
  };
  auto stageB = [&](int buf, int h, int tg) {
    const int kb = tg * 64 + h * 32;
#pragma unroll
    for (int j = 0; j < 2; ++j)
      gload_lds16(Wb + kb + laneB[j], &smB[buf][h][(w * 32 + j * 16) * 32]);
  };

  auto ridx = [&](int r) { return r * 32 + ((lkg ^ ((r >> 1) & 3)) << 3); };

  f32x4 acc[8][4] = {};
  s16x8 bfr[4], afr[4];

  // prologue: tile qb (4 halves) + tile qb+1 (h0 halves) = 6 stages, 12 loads
  stageA(0, 0, qb); stageB(0, 0, qb);
  stageA(0, 1, qb); stageB(0, 1, qb);
  stageA(1, 0, qb + 1); stageB(1, 0, qb + 1);
  asm volatile("s_waitcnt vmcnt(8)" ::: "memory");
  __builtin_amdgcn_s_barrier();

#pragma unroll 1
  for (int tt = 0; tt < NTL; ++tt) {
    const int buf = tt & 1;
    const int tg = qb + tt;
    // ---- P0: ks0, m-lower ----
#pragma unroll
    for (int n = 0; n < 4; ++n)
      bfr[n] = *(const s16x8*)&smB[buf][0][ridx(wc * 64 + n * 16 + lrow)];
#pragma unroll
    for (int m = 0; m < 4; ++m)
      afr[m] = *(const s16x8*)&smA[buf][0][ridx(wr * 128 + m * 16 + lrow)];
    if (tt + 1 < NTL) stageA(buf ^ 1, 1, tg + 1);
    __builtin_amdgcn_s_barrier();
    __builtin_amdgcn_s_setprio(1);
#pragma unroll
    for (int m = 0; m < 4; ++m)
#pragma unroll
      for (int n = 0; n < 4; ++n)
        acc[m][n] = __builtin_amdgcn_mfma_f32_16x16x32_bf16(afr[m], bfr[n], acc[m][n], 0, 0, 0);
    __builtin_amdgcn_s_setprio(0);
    __builtin_amdgcn_s_barrier();
    // ---- P1: ks0, m-upper (B kept in regs) ----
#pragma unroll
    for (int m = 0; m < 4; ++m)
      afr[m] = *(const s16x8*)&smA[buf][0][ridx(wr * 128 + (4 + m) * 16 + lrow)];
    if (tt + 1 < NTL) stageB(buf ^ 1, 1, tg + 1);
    __builtin_amdgcn_s_barrier();
    __builtin_amdgcn_s_setprio(1);
#pragma unroll
    for (int m = 0; m < 4; ++m)
#pragma unroll
      for (int n = 0; n < 4; ++n)
        acc[4 + m][n] = __builtin_amdgcn_mfma_f32_16x16x32_bf16(afr[m], bfr[n], acc[4 + m][n], 0, 0, 0);
    __builtin_amdgcn_s_setprio(0);
    if (tt + 1 < NTL) asm volatile("s_waitcnt vmcnt(8)" ::: "memory");
    else asm volatile("s_waitcnt vmcnt(0)" ::: "memory");
    __builtin_amdgcn_s_barrier();
    // ---- P2: ks1, m-lower ----
#pragma unroll
    for (int n = 0; n < 4; ++n)
      bfr[n] = *(const s16x8*)&smB[buf][1][ridx(wc * 64 + n * 16 + lrow)];
#pragma unroll
    for (int m = 0; m < 4; ++m)
      afr[m] = *(const s16x8*)&smA[buf][1][ridx(wr * 128 + m * 16 + lrow)];
    if (tt + 2 < NTL) stageA(buf, 0, tg + 2);
    __builtin_amdgcn_s_barrier();
    __builtin_amdgcn_s_setprio(1);
#pragma unroll
    for (int m = 0; m < 4; ++m)
#pragma unroll
      for (int n = 0; n < 4; ++n)
        acc[m][n] = __builtin_amdgcn_mfma_f32_16x16x32_bf16(afr[m], bfr[n], acc[m][n], 0, 0, 0);
    __builtin_amdgcn_s_setprio(0);
    __builtin_amdgcn_s_barrier();
    // ---- P3: ks1, m-upper ----
#pragma unroll
    for (int m = 0; m < 4; ++m)
      afr[m] = *(const s16x8*)&smA[buf][1][ridx(wr * 128 + (4 + m) * 16 + lrow)];
    if (tt + 2 < NTL) stageB(buf, 0, tg + 2);
    __builtin_amdgcn_s_barrier();
    __builtin_amdgcn_s_setprio(1);
#pragma unroll
    for (int m = 0; m < 4; ++m)
#pragma unroll
      for (int n = 0; n < 4; ++n)
        acc[4 + m][n] = __builtin_amdgcn_mfma_f32_16x16x32_bf16(afr[m], bfr[n], acc[4 + m][n], 0, 0, 0);
    __builtin_amdgcn_s_setprio(0);
    if (tt + 2 < NTL) asm volatile("s_waitcnt vmcnt(8)" ::: "memory");
    else if (tt + 1 < NTL) asm volatile("s_waitcnt vmcnt(4)" ::: "memory");
    else asm volatile("s_waitcnt vmcnt(0)" ::: "memory");
    __builtin_amdgcn_s_barrier();
  }

  ushort* outp = Xout;
  if constexpr (MODE == 3) outp += (size_t)kp * GSZ * NPT * OPAD;
#pragma unroll
  for (int m = 0; m < 8; ++m) {
#pragma unroll
    for (int n = 0; n < 4; ++n) {
      const int oc = o0 + wc * 64 + n * 16 + lrow;
      const float bv = (MODE == 0) ? bias[oc] : 0.f;
#pragma unroll
      for (int r = 0; r < 4; ++r) {
        const int row = n0 + wr * 128 + m * 16 + lkg * 4 + r;
        float v = acc[m][n][r] + bv;
        if (MODE == 0 && RELU) v = v > 0.f ? v : 0.f;
        outp[((size_t)g * NPT + row) * OPAD + oc] = f2bf(v);
      }
    }
  }
}

// H1 += PK0 + PK1 + bias (L3 split-K combine), vectorized x8
__global__ __launch_bounds__(256) void combine_k(ushort* __restrict__ H1,
                                                 const ushort* __restrict__ PK,
                                                 const float* __restrict__ bias) {
  constexpr size_t TOT = (size_t)GSZ * NPT * 256;
  const size_t i = ((size_t)blockIdx.x * 256 + threadIdx.x) * 8;
  if (i >= TOT) return;
  const int oc = (int)(i & 255);
  u16x8 h = *(const u16x8*)&H1[i];
  u16x8 p0 = *(const u16x8*)&PK[i];
  u16x8 p1 = *(const u16x8*)&PK[TOT + i];
  u16x8 o;
#pragma unroll
  for (int j = 0; j < 8; ++j)
    o[j] = f2bf(bf2f(h[j]) + bf2f(p0[j]) + bf2f(p1[j]) + bias[oc + j]);
  *(u16x8*)&H1[i] = o;
}

// Eq4: 4 split-K partials [4][G][N][64] fp32 -> out: inv [N][32], eqv [N][32][G]
__global__ __launch_bounds__(256) void finalize_k(const float* __restrict__ Eq,
                                                  float* __restrict__ out) {
  const int n = blockIdx.x;
  const int t = threadIdx.x;
  const int c = t & 31;
  const int gs = t >> 5;
  constexpr size_t PART = (size_t)GSZ * NPT * 64;

  float invp = 0.f;
  for (int g = gs; g < GSZ; g += 8) {
    const size_t base = ((size_t)g * NPT + n) * 64 + c;
    float x = Eq[base] + Eq[PART + base] + Eq[2 * PART + base] + Eq[3 * PART + base];
    invp += x;
    float ss = x * x;
#pragma unroll
    for (int m = 16; m >= 1; m >>= 1) ss += __shfl_xor(ss, m, 64);
    float nrm = sqrtf(ss);
    nrm = nrm > 1e-4f ? nrm : 1e-4f;
    out[16384 + ((size_t)n * 32 + c) * GSZ + g] = x / nrm;
  }

  __shared__ float tmp[8][32];
  tmp[gs][c] = invp;
  __syncthreads();
  if (t < 32) {
    float s = 0.f;
#pragma unroll
    for (int i = 0; i < 8; ++i) s += tmp[i][t];
    s *= (1.f / 60.f);
    float ss = s * s;
#pragma unroll
    for (int m = 16; m >= 1; m >>= 1) ss += __shfl_xor(ss, m, 64);
    float nrm = sqrtf(ss);
    nrm = nrm > 1e-4f ? nrm : 1e-4f;
    out[(size_t)n * 32 + t] = s / nrm;
  }
}

extern "C" void kernel_launch(void* const* d_in, const int* in_sizes, int n_in,
                              void* d_out, int out_size, void* d_ws, size_t ws_size,
                              hipStream_t stream) {
  const float* feats = (const float*)d_in[0];
  const int* nei = (const int*)d_in[1];
  const float* W_in = (const float*)d_in[2];
  const float* b_in = (const float*)d_in[3];
  const float* W_r1 = (const float*)d_in[4];
  const float* b_r1 = (const float*)d_in[5];
  const float* W_r2 = (const float*)d_in[6];
  const float* b_r2 = (const float*)d_in[7];
  const float* W_out = (const float*)d_in[8];
  const float* b_out = (const float*)d_in[9];
  float* out = (float*)d_out;

  char* ws = (char*)d_ws;
  size_t off = 0;
  auto alloc = [&](size_t bytes) {
    void* p = ws + off;
    off += (bytes + 255) & ~(size_t)255;
    return p;
  };
  ushort* X0 = (ushort*)alloc((size_t)61 * NPT * 32 * 2);     // 2.0 MB
  ushort* H1 = (ushort*)alloc((size_t)GSZ * NPT * 256 * 2);   // 15.7 MB (h1 -> h2)
  ushort* R = (ushort*)alloc((size_t)GSZ * NPT * 512 * 2);    // 31.5 MB; Eq4 alias after L3
  ushort* PK = (ushort*)alloc((size_t)2 * GSZ * NPT * 256 * 2);  // 31.5 MB L3 partials
  ushort* Wb_in = (ushort*)alloc((size_t)256 * 448 * 2);
  ushort* Wb_r1 = (ushort*)alloc((size_t)512 * 3328 * 2);
  ushort* Wb_r2 = (ushort*)alloc((size_t)256 * 6656 * 2);
  ushort* Wb_out = (ushort*)alloc((size_t)64 * 3328 * 2);
  float* Eq4 = (float*)R;  // [4][G][N][64] fp32, reuses R (dead after combine)

  prep_feats_k<<<(61 * NPT * 32 + 255) / 256, 256, 0, stream>>>(feats, X0);
  prep_wb_k<<<(256 * 448 + 255) / 256, 256, 0, stream>>>(W_in, Wb_in, 256, 256, 32, 448);
  prep_wb_k<<<(512 * 3328 + 255) / 256, 256, 0, stream>>>(W_r1, Wb_r1, 512, 512, 256, 3328);
  prep_wb_k<<<(256 * 6656 + 255) / 256, 256, 0, stream>>>(W_r2, Wb_r2, 256, 256, 512, 6656);
  prep_wb_k<<<(64 * 3328 + 255) / 256, 256, 0, stream>>>(W_out, Wb_out, 32, 64, 256, 3328);

  // L1: 32 -> 256 (KTOT 448, 7 chunks), 4-wave dbuf, grid 480
  comb_gemm<32, 448, 256, 256, 128, 0, false><<<dim3(2 * 4 * GSZ), dim3(256), 0, stream>>>(
      X0, Wb_in, b_in, nei, H1, nullptr, nullptr, 0, 7);
  // L2: 256 -> 512, relu; 8-phase 256x256, grid 240
  comb8p256<256, 3328, 512, 0, true, 1><<<dim3(240), dim3(512), 0, stream>>>(
      H1, Wb_r1, b_r1, nei, R);
  // L3: 512 -> 256, split-K x2 raw partials; 8-phase 256x256, grid 240
  comb8p256<512, 6656, 256, 3, false, 2><<<dim3(240), dim3(512), 0, stream>>>(
      R, Wb_r2, b_r2, nei, PK);
  // combine: h2 = h1 + p0 + p1 + bias
  combine_k<<<dim3((GSZ * NPT * 256 / 8 + 255) / 256), dim3(256), 0, stream>>>(H1, PK, b_r2);
  // L4: 256 -> 32 (pad 64), split-K x4 -> Eq4 partials (R region)
  for (int kp = 0; kp < 4; ++kp) {
    comb_gemm<256, 3328, 64, 32, 64, 2, false><<<dim3(1 * 4 * GSZ), dim3(256), 0, stream>>>(
        H1, Wb_out, b_out, nei, nullptr, Eq4 + (size_t)kp * GSZ * NPT * 64,
        kp == 0 ? feats : nullptr, kp * 13, (kp + 1) * 13);
  }
  finalize_k<<<NPT, 256, 0, stream>>>(Eq4, out);
}

// Round 9
// 354.284 us; speedup vs baseline: 1.0197x; 1.0197x over previous
//
#include <hip/hip_runtime.h>
#include <stdint.h>

#define GSZ 60
#define KNB 13
#define NPT 512

typedef __attribute__((ext_vector_type(4))) float f32x4;
typedef __attribute__((ext_vector_type(8))) short s16x8;

__device__ __forceinline__ ushort f2bf(float f) {
  union { float f; unsigned u; } v; v.f = f;
  unsigned r = v.u + 0x7fffu + ((v.u >> 16) & 1u);
  return (ushort)(r >> 16);
}
__device__ __forceinline__ float bf2f(ushort h) {
  union { unsigned u; float f; } v; v.u = ((unsigned)h) << 16;
  return v.f;
}

// async global->LDS, 16B per lane; dst wave-uniform (HW adds lane*16)
__device__ __forceinline__ void gload_lds16(const void* gsrc, void* ldst) {
  __builtin_amdgcn_global_load_lds(
      (const __attribute__((address_space(1))) uint32_t*)gsrc,
      (__attribute__((address_space(3))) uint32_t*)ldst, 16, 0, 0);
}

// ---- merged prep: all weight transposes + feats pack in ONE launch ----
// seg layout (element counts):
//  S0 Wb_in  [256][448],  S1 Wb_r1 [512][3328], S2 Wb_r2 [256][6656],
//  S3 Wb_out [64][3328],  S4 X0    [61][512][32]
__global__ __launch_bounds__(256) void prep_all_k(
    const float* __restrict__ W_in, const float* __restrict__ W_r1,
    const float* __restrict__ W_r2, const float* __restrict__ W_out,
    const float* __restrict__ feats,
    ushort* __restrict__ Wb_in, ushort* __restrict__ Wb_r1,
    ushort* __restrict__ Wb_r2, ushort* __restrict__ Wb_out,
    ushort* __restrict__ X0) {
  constexpr int N0 = 256 * 448;
  constexpr int N1 = 512 * 3328;
  constexpr int N2 = 256 * 6656;
  constexpr int N3 = 64 * 3328;
  constexpr int N4 = 61 * NPT * 32;
  int idx = blockIdx.x * 256 + threadIdx.x;
  if (idx < N0) {
    int o = idx / 448, kk = idx - o * 448, k = kk / 32, c = kk - k * 32;
    Wb_in[idx] = (k < KNB) ? f2bf(W_in[(o * 32 + c) * KNB + k]) : (ushort)0;
    return;
  }
  idx -= N0;
  if (idx < N1) {
    int o = idx / 3328, kk = idx - o * 3328, k = kk / 256, c = kk - k * 256;
    Wb_r1[idx] = f2bf(W_r1[(o * 256 + c) * KNB + k]);
    return;
  }
  idx -= N1;
  if (idx < N2) {
    int o = idx / 6656, kk = idx - o * 6656, k = kk / 512, c = kk - k * 512;
    Wb_r2[idx] = f2bf(W_r2[(o * 512 + c) * KNB + k]);
    return;
  }
  idx -= N2;
  if (idx < N3) {
    int o = idx / 3328, kk = idx - o * 3328, k = kk / 256, c = kk - k * 256;
    Wb_out[idx] = (o < 32) ? f2bf(W_out[(o * 256 + c) * KNB + k]) : (ushort)0;
    return;
  }
  idx -= N3;
  if (idx < N4) {
    int c = idx & 31, t = idx >> 5, n = t % NPT, g = t / NPT;
    X0[idx] = (g < GSZ) ? f2bf(feats[(n * 32 + c) * GSZ + g]) : (ushort)0;
  }
}

// ---------------- 4-wave 128xBN BK=64 dbuf kernel (L1, L3, L4 split-K) — proven ----------------
template <int CIN, int KTOT, int OPAD, int OREAL, int BN, int MODE, bool RELU>
__global__ __launch_bounds__(256) void comb_gemm(
    const ushort* __restrict__ Xin, const ushort* __restrict__ Wb,
    const float* __restrict__ bias, const int* __restrict__ nei,
    ushort* __restrict__ Xout, float* __restrict__ Eq,
    const float* __restrict__ feats, int qb, int qe) {
  constexpr int BM = 128;
  constexpr int BK = 64;
  constexpr int TO = OPAD / BN;
  constexpr int TN = NPT / BM;
  constexpr int WN = BN / 2;
  constexpr int N_REP = WN / 16;
  constexpr int M_REP = 4;
  constexpr int CSH = (CIN == 32) ? 5 : (CIN == 256) ? 8 : 9;
  static_assert(CIN == (1 << CSH), "CIN pow2");

  __shared__ ushort smA[2][BM * BK];
  __shared__ ushort smB[2][BN * BK];
  __shared__ int nei_sh[16];

  const int nwg = TO * TN * GSZ;
  const int cpx = nwg >> 3;
  const int bid = blockIdx.x;
  const int idx = (bid & 7) * cpx + (bid >> 3);
  const int g = idx / (TO * TN);
  const int rem = idx - g * (TO * TN);
  const int nt = rem / TO;
  const int ot = rem - nt * TO;
  const int n0 = nt * BM;
  const int o0 = ot * BN;

  const int t = threadIdx.x;
  if (t < 14) nei_sh[t] = (t < KNB) ? nei[g * KNB + t] : GSZ;
  __syncthreads();

  const int w = t >> 6;
  const int l = t & 63;
  const int lrow = l & 15;
  const int lkg = l >> 4;
  const int wr = w >> 1;
  const int wc = w & 1;
  const int srow_w = w * 8;
  const int sr = l >> 3;
  const int slot = l & 7;

  int laneA[BM / 32], laneB[BN / 32], swz[BM / 32];
#pragma unroll
  for (int j = 0; j < BM / 32; ++j) {
    const int r = j * 32 + srow_w + sr;
    swz[j] = (slot ^ (r & 7)) << 3;
    laneA[j] = ((n0 + r) << CSH) + swz[j];
  }
#pragma unroll
  for (int j = 0; j < BN / 32; ++j) {
    const int r = j * 32 + srow_w + sr;
    laneB[j] = (o0 + r) * KTOT + ((slot ^ (r & 7)) << 3);
  }

  auto stage = [&](int buf, int q) {
    const int c0 = q * BK;
    if constexpr (CIN >= 64) {
      const int pbase = nei_sh[c0 >> CSH] * (NPT << CSH) + (c0 & (CIN - 1));
#pragma unroll
      for (int j = 0; j < BM / 32; ++j)
        gload_lds16(Xin + pbase + laneA[j], &smA[buf][(j * 32 + srow_w) * BK]);
    } else {
#pragma unroll
      for (int j = 0; j < BM / 32; ++j) {
        const int r = j * 32 + srow_w + sr;
        const int kk = c0 + swz[j];
        const int nbr = kk >> CSH;
        const int cc = kk & (CIN - 1);
        gload_lds16(Xin + ((nei_sh[nbr] * NPT + n0 + r) << CSH) + cc,
                    &smA[buf][(j * 32 + srow_w) * BK]);
      }
    }
#pragma unroll
    for (int j = 0; j < BN / 32; ++j)
      gload_lds16(Wb + laneB[j] + c0, &smB[buf][(j * 32 + srow_w) * BK]);
  };

  f32x4 acc[M_REP][N_REP] = {};

  stage(0, qb);
  asm volatile("s_waitcnt vmcnt(0)" ::: "memory");
  __builtin_amdgcn_s_barrier();

  int cur = 0;
#pragma unroll 1
  for (int q = qb; q < qe; ++q) {
    if (q + 1 < qe) stage(cur ^ 1, q + 1);
#pragma unroll
    for (int ks = 0; ks < 2; ++ks) {
      const int cb = ks * 4 + lkg;
      s16x8 bf[N_REP];
#pragma unroll
      for (int n = 0; n < N_REP; ++n) {
        const int r = wc * WN + n * 16 + lrow;
        bf[n] = *(const s16x8*)&smB[cur][r * BK + ((cb ^ (r & 7)) << 3)];
      }
#pragma unroll
      for (int m = 0; m < M_REP; ++m) {
        const int r = wr * 64 + m * 16 + lrow;
        s16x8 af = *(const s16x8*)&smA[cur][r * BK + ((cb ^ (r & 7)) << 3)];
#pragma unroll
        for (int n = 0; n < N_REP; ++n)
          acc[m][n] = __builtin_amdgcn_mfma_f32_16x16x32_bf16(af, bf[n], acc[m][n], 0, 0, 0);
      }
    }
    asm volatile("s_waitcnt vmcnt(0)" ::: "memory");
    __builtin_amdgcn_s_barrier();
    cur ^= 1;
  }

#pragma unroll
  for (int m = 0; m < M_REP; ++m) {
#pragma unroll
    for (int n = 0; n < N_REP; ++n) {
      const int oc = o0 + wc * WN + n * 16 + lrow;
      float bv;
      if (MODE == 2)
        bv = (oc < OREAL && feats) ? bias[oc] : 0.f;
      else
        bv = bias[oc];
#pragma unroll
      for (int r = 0; r < 4; ++r) {
        const int row = n0 + wr * 64 + m * 16 + lkg * 4 + r;
        float v = acc[m][n][r] + bv;
        if (MODE == 0) {
          if (RELU) v = v > 0.f ? v : 0.f;
          Xout[((size_t)g * NPT + row) * OPAD + oc] = f2bf(v);
        } else if (MODE == 1) {
          const size_t ix = ((size_t)g * NPT + row) * OPAD + oc;
          Xout[ix] = f2bf(bf2f(Xout[ix]) + v);
        } else {
          const float add = (oc < OREAL && feats) ? feats[((size_t)row * 32 + oc) * GSZ + g] : 0.f;
          Eq[((size_t)g * NPT + row) * 64 + oc] = v + add;
        }
      }
    }
  }
}

// ---------------- 4-wave 128x128 BK=32 kernel: 33 KB LDS -> 4 blocks/CU (L2) ----------------
// Same dbuf/sync skeleton as comb_gemm; K-chunk = 32 (one 16x16x32 MFMA k-step).
// LDS row = 64 B (4 x 16B slots); swizzle: LDS slot s of row r holds global slot s^(r&3).
template <int CIN, int KTOT, int OPAD, int MODE, bool RELU>
__global__ __launch_bounds__(256, 4) void comb_bk32(
    const ushort* __restrict__ Xin, const ushort* __restrict__ Wb,
    const float* __restrict__ bias, const int* __restrict__ nei,
    ushort* __restrict__ Xout) {
  constexpr int BM = 128, BN = 128, BK = 32;
  constexpr int NCH = KTOT / BK;
  constexpr int TO = OPAD / BN;
  constexpr int TN = NPT / BM;  // 4
  constexpr int CSH = (CIN == 256) ? 8 : 9;
  static_assert(CIN == (1 << CSH), "CIN pow2");

  __shared__ ushort smA[2][BM * BK];  // 16 KB
  __shared__ ushort smB[2][BN * BK];  // 16 KB
  __shared__ int nei_sh[16];

  const int nwg = TO * TN * GSZ;
  const int cpx = nwg >> 3;
  const int bid = blockIdx.x;
  const int idx = (bid & 7) * cpx + (bid >> 3);
  const int g = idx / (TO * TN);
  const int rem = idx - g * (TO * TN);
  const int nt = rem / TO;
  const int ot = rem - nt * TO;
  const int n0 = nt * BM;
  const int o0 = ot * BN;

  const int t = threadIdx.x;
  if (t < 14) nei_sh[t] = (t < KNB) ? nei[g * KNB + t] : GSZ;
  __syncthreads();

  const int w = t >> 6;
  const int l = t & 63;
  const int lrow = l & 15;
  const int lkg = l >> 4;  // k 16B slot 0..3
  const int wr = w >> 1;
  const int wc = w & 1;

  // staging: per instr, 64 lanes cover 16 rows x 64 B; lane l -> row base+(l>>2), slot l&3.
  // source pre-inverse-swizzled: global slot = (l&3) ^ ((l>>2)&3)
  const int sgl = ((l & 3) ^ ((l >> 2) & 3)) << 3;  // element offset
  int laneA[2], laneB[2];
#pragma unroll
  for (int j = 0; j < 2; ++j) {
    const int r = (w * 2 + j) * 16 + (l >> 2);
    laneA[j] = ((n0 + r) << CSH) + sgl;
    laneB[j] = (o0 + r) * KTOT + sgl;
  }

  auto stage = [&](int buf, int q) {
    const int c0 = q * BK;
    const int pbase = nei_sh[c0 >> CSH] * (NPT << CSH) + (c0 & (CIN - 1));
#pragma unroll
    for (int j = 0; j < 2; ++j)
      gload_lds16(Xin + pbase + laneA[j], &smA[buf][(w * 2 + j) * 16 * BK]);
#pragma unroll
    for (int j = 0; j < 2; ++j)
      gload_lds16(Wb + c0 + laneB[j], &smB[buf][(w * 2 + j) * 16 * BK]);
  };

  // swizzled ds_read address (ushorts): row r, lane k-slot lkg
  auto ridx = [&](int r) { return r * BK + ((lkg ^ (r & 3)) << 3); };

  f32x4 acc[4][4] = {};

  stage(0, 0);
  asm volatile("s_waitcnt vmcnt(0)" ::: "memory");
  __builtin_amdgcn_s_barrier();

  int cur = 0;
#pragma unroll 1
  for (int q = 0; q < NCH; ++q) {
    if (q + 1 < NCH) stage(cur ^ 1, q + 1);
    s16x8 bf[4];
#pragma unroll
    for (int n = 0; n < 4; ++n)
      bf[n] = *(const s16x8*)&smB[cur][ridx(wc * 64 + n * 16 + lrow)];
#pragma unroll
    for (int m = 0; m < 4; ++m) {
      s16x8 af = *(const s16x8*)&smA[cur][ridx(wr * 64 + m * 16 + lrow)];
#pragma unroll
      for (int n = 0; n < 4; ++n)
        acc[m][n] = __builtin_amdgcn_mfma_f32_16x16x32_bf16(af, bf[n], acc[m][n], 0, 0, 0);
    }
    asm volatile("s_waitcnt vmcnt(0)" ::: "memory");
    __builtin_amdgcn_s_barrier();
    cur ^= 1;
  }

#pragma unroll
  for (int m = 0; m < 4; ++m) {
#pragma unroll
    for (int n = 0; n < 4; ++n) {
      const int oc = o0 + wc * 64 + n * 16 + lrow;
      const float bv = bias[oc];
#pragma unroll
      for (int r = 0; r < 4; ++r) {
        const int row = n0 + wr * 64 + m * 16 + lkg * 4 + r;
        float v = acc[m][n][r] + bv;
        if (MODE == 0) {
          if (RELU) v = v > 0.f ? v : 0.f;
          Xout[((size_t)g * NPT + row) * OPAD + oc] = f2bf(v);
        } else {  // MODE 1
          const size_t ix = ((size_t)g * NPT + row) * OPAD + oc;
          Xout[ix] = f2bf(bf2f(Xout[ix]) + v);
        }
      }
    }
  }
}

// Eq4: 4 split-K partials [4][G][N][64] fp32 -> out: inv [N][32], eqv [N][32][G]
__global__ __launch_bounds__(256) void finalize_k(const float* __restrict__ Eq,
                                                  float* __restrict__ out) {
  const int n = blockIdx.x;
  const int t = threadIdx.x;
  const int c = t & 31;
  const int gs = t >> 5;
  constexpr size_t PART = (size_t)GSZ * NPT * 64;

  float invp = 0.f;
  for (int g = gs; g < GSZ; g += 8) {
    const size_t base = ((size_t)g * NPT + n) * 64 + c;
    float x = Eq[base] + Eq[PART + base] + Eq[2 * PART + base] + Eq[3 * PART + base];
    invp += x;
    float ss = x * x;
#pragma unroll
    for (int m = 16; m >= 1; m >>= 1) ss += __shfl_xor(ss, m, 64);
    float nrm = sqrtf(ss);
    nrm = nrm > 1e-4f ? nrm : 1e-4f;
    out[16384 + ((size_t)n * 32 + c) * GSZ + g] = x / nrm;
  }

  __shared__ float tmp[8][32];
  tmp[gs][c] = invp;
  __syncthreads();
  if (t < 32) {
    float s = 0.f;
#pragma unroll
    for (int i = 0; i < 8; ++i) s += tmp[i][t];
    s *= (1.f / 60.f);
    float ss = s * s;
#pragma unroll
    for (int m = 16; m >= 1; m >>= 1) ss += __shfl_xor(ss, m, 64);
    float nrm = sqrtf(ss);
    nrm = nrm > 1e-4f ? nrm : 1e-4f;
    out[(size_t)n * 32 + t] = s / nrm;
  }
}

extern "C" void kernel_launch(void* const* d_in, const int* in_sizes, int n_in,
                              void* d_out, int out_size, void* d_ws, size_t ws_size,
                              hipStream_t stream) {
  const float* feats = (const float*)d_in[0];
  const int* nei = (const int*)d_in[1];
  const float* W_in = (const float*)d_in[2];
  const float* b_in = (const float*)d_in[3];
  const float* W_r1 = (const float*)d_in[4];
  const float* b_r1 = (const float*)d_in[5];
  const float* W_r2 = (const float*)d_in[6];
  const float* b_r2 = (const float*)d_in[7];
  const float* W_out = (const float*)d_in[8];
  const float* b_out = (const float*)d_in[9];
  float* out = (float*)d_out;

  char* ws = (char*)d_ws;
  size_t off = 0;
  auto alloc = [&](size_t bytes) {
    void* p = ws + off;
    off += (bytes + 255) & ~(size_t)255;
    return p;
  };
  ushort* X0 = (ushort*)alloc((size_t)61 * NPT * 32 * 2);    // 2.0 MB
  ushort* H1 = (ushort*)alloc((size_t)GSZ * NPT * 256 * 2);  // 15.7 MB (h1 -> h2)
  ushort* R = (ushort*)alloc((size_t)GSZ * NPT * 512 * 2);   // 31.5 MB; Eq4 alias after L3
  ushort* Wb_in = (ushort*)alloc((size_t)256 * 448 * 2);
  ushort* Wb_r1 = (ushort*)alloc((size_t)512 * 3328 * 2);
  ushort* Wb_r2 = (ushort*)alloc((size_t)256 * 6656 * 2);
  ushort* Wb_out = (ushort*)alloc((size_t)64 * 3328 * 2);
  float* Eq4 = (float*)R;  // [4][G][N][64] fp32, reuses R (dead after L3)

  // merged prep: one launch
  constexpr int PREP_TOT = 256 * 448 + 512 * 3328 + 256 * 6656 + 64 * 3328 + 61 * NPT * 32;
  prep_all_k<<<dim3((PREP_TOT + 255) / 256), dim3(256), 0, stream>>>(
      W_in, W_r1, W_r2, W_out, feats, Wb_in, Wb_r1, Wb_r2, Wb_out, X0);

  // L1: 32 -> 256 (KTOT 448, 7 chunks), 4-wave BK=64, grid 480
  comb_gemm<32, 448, 256, 256, 128, 0, false><<<dim3(2 * 4 * GSZ), dim3(256), 0, stream>>>(
      X0, Wb_in, b_in, nei, H1, nullptr, nullptr, 0, 7);
  // L2: 256 -> 512, relu; BK=32 high-residency kernel, grid 960 (4 blk/CU)
  comb_bk32<256, 3328, 512, 0, true><<<dim3(4 * 4 * GSZ), dim3(256), 0, stream>>>(
      H1, Wb_r1, b_r1, nei, R);
  // L3 (control): 512 -> 256, h2 = h1 + comb(r); proven BK=64 kernel, grid 480
  comb_gemm<512, 6656, 256, 256, 128, 1, false><<<dim3(2 * 4 * GSZ), dim3(256), 0, stream>>>(
      R, Wb_r2, b_r2, nei, H1, nullptr, nullptr, 0, 104);
  // L4: 256 -> 32 (pad 64), split-K x4 -> Eq4 partials (R region)
  for (int kp = 0; kp < 4; ++kp) {
    comb_gemm<256, 3328, 64, 32, 64, 2, false><<<dim3(1 * 4 * GSZ), dim3(256), 0, stream>>>(
        H1, Wb_out, b_out, nei, nullptr, Eq4 + (size_t)kp * GSZ * NPT * 64,
        kp == 0 ? feats : nullptr, kp * 13, (kp + 1) * 13);
  }
  finalize_k<<<NPT, 256, 0, stream>>>(Eq4, out);
}

// Round 10
// 321.986 us; speedup vs baseline: 1.1220x; 1.1003x over previous
//
#include <hip/hip_runtime.h>
#include <stdint.h>

#define GSZ 60
#define KNB 13
#define NPT 512

typedef __attribute__((ext_vector_type(4))) float f32x4;
typedef __attribute__((ext_vector_type(8))) short s16x8;

__device__ __forceinline__ ushort f2bf(float f) {
  union { float f; unsigned u; } v; v.f = f;
  unsigned r = v.u + 0x7fffu + ((v.u >> 16) & 1u);
  return (ushort)(r >> 16);
}
__device__ __forceinline__ float bf2f(ushort h) {
  union { unsigned u; float f; } v; v.u = ((unsigned)h) << 16;
  return v.f;
}

// async global->LDS, 16B per lane; dst wave-uniform (HW adds lane*16)
__device__ __forceinline__ void gload_lds16(const void* gsrc, void* ldst) {
  __builtin_amdgcn_global_load_lds(
      (const __attribute__((address_space(1))) uint32_t*)gsrc,
      (__attribute__((address_space(3))) uint32_t*)ldst, 16, 0, 0);
}

// ---- merged prep: all weight transposes + feats pack in ONE launch ----
__global__ __launch_bounds__(256) void prep_all_k(
    const float* __restrict__ W_in, const float* __restrict__ W_r1,
    const float* __restrict__ W_r2, const float* __restrict__ W_out,
    const float* __restrict__ feats,
    ushort* __restrict__ Wb_in, ushort* __restrict__ Wb_r1,
    ushort* __restrict__ Wb_r2, ushort* __restrict__ Wb_out,
    ushort* __restrict__ X0) {
  constexpr int N0 = 256 * 448;
  constexpr int N1 = 512 * 3328;
  constexpr int N2 = 256 * 6656;
  constexpr int N3 = 64 * 3328;
  constexpr int N4 = 61 * NPT * 32;
  int idx = blockIdx.x * 256 + threadIdx.x;
  if (idx < N0) {
    int o = idx / 448, kk = idx - o * 448, k = kk / 32, c = kk - k * 32;
    Wb_in[idx] = (k < KNB) ? f2bf(W_in[(o * 32 + c) * KNB + k]) : (ushort)0;
    return;
  }
  idx -= N0;
  if (idx < N1) {
    int o = idx / 3328, kk = idx - o * 3328, k = kk / 256, c = kk - k * 256;
    Wb_r1[idx] = f2bf(W_r1[(o * 256 + c) * KNB + k]);
    return;
  }
  idx -= N1;
  if (idx < N2) {
    int o = idx / 6656, kk = idx - o * 6656, k = kk / 512, c = kk - k * 512;
    Wb_r2[idx] = f2bf(W_r2[(o * 512 + c) * KNB + k]);
    return;
  }
  idx -= N2;
  if (idx < N3) {
    int o = idx / 3328, kk = idx - o * 3328, k = kk / 256, c = kk - k * 256;
    Wb_out[idx] = (o < 32) ? f2bf(W_out[(o * 256 + c) * KNB + k]) : (ushort)0;
    return;
  }
  idx -= N3;
  if (idx < N4) {
    int c = idx & 31, t = idx >> 5, n = t % NPT, g = t / NPT;
    X0[idx] = (g < GSZ) ? f2bf(feats[(n * 32 + c) * GSZ + g]) : (ushort)0;
  }
}

// ---------------- 4-wave 128xBN BK=64 dbuf kernel — proven r3 structure ----------------
// SPLITK=1: chunks [qb,qe). SPLITK=4: one dispatch, grid = 4*TO*TN*GSZ; kp derived
// XCD-locally from the swizzled index; part kp does chunks [kp*13, kp*13+13),
// MODE 2 writes partial kp at Eq + kp*G*N*64; bias+feats added only in part 0.
template <int CIN, int KTOT, int OPAD, int OREAL, int BN, int MODE, bool RELU, int SPLITK>
__global__ __launch_bounds__(256) void comb_gemm(
    const ushort* __restrict__ Xin, const ushort* __restrict__ Wb,
    const float* __restrict__ bias, const int* __restrict__ nei,
    ushort* __restrict__ Xout, float* __restrict__ Eq,
    const float* __restrict__ feats, int qb, int qe) {
  constexpr int BM = 128;
  constexpr int BK = 64;
  constexpr int TO = OPAD / BN;
  constexpr int TN = NPT / BM;
  constexpr int WN = BN / 2;
  constexpr int N_REP = WN / 16;
  constexpr int M_REP = 4;
  constexpr int CSH = (CIN == 32) ? 5 : (CIN == 256) ? 8 : 9;
  static_assert(CIN == (1 << CSH), "CIN pow2");

  __shared__ ushort smA[2][BM * BK];
  __shared__ ushort smB[2][BN * BK];
  __shared__ int nei_sh[16];

  const int nparts = TO * TN * GSZ;
  const int nwg = nparts * SPLITK;
  const int cpx = nwg >> 3;
  const int bid = blockIdx.x;
  const int idx = (bid & 7) * cpx + (bid >> 3);
  int kp = 0, sub = idx;
  if constexpr (SPLITK > 1) {
    kp = idx / nparts;
    sub = idx - kp * nparts;
    constexpr int CHP = (KTOT / BK) / SPLITK;
    qb = kp * CHP;
    qe = qb + CHP;
  }
  const int g = sub / (TO * TN);
  const int rem = sub - g * (TO * TN);
  const int nt = rem / TO;
  const int ot = rem - nt * TO;
  const int n0 = nt * BM;
  const int o0 = ot * BN;
  const bool addf = (SPLITK == 1) || (kp == 0);

  const int t = threadIdx.x;
  if (t < 14) nei_sh[t] = (t < KNB) ? nei[g * KNB + t] : GSZ;
  __syncthreads();

  const int w = t >> 6;
  const int l = t & 63;
  const int lrow = l & 15;
  const int lkg = l >> 4;
  const int wr = w >> 1;
  const int wc = w & 1;
  const int srow_w = w * 8;
  const int sr = l >> 3;
  const int slot = l & 7;

  int laneA[BM / 32], laneB[BN / 32], swz[BM / 32];
#pragma unroll
  for (int j = 0; j < BM / 32; ++j) {
    const int r = j * 32 + srow_w + sr;
    swz[j] = (slot ^ (r & 7)) << 3;
    laneA[j] = ((n0 + r) << CSH) + swz[j];
  }
#pragma unroll
  for (int j = 0; j < BN / 32; ++j) {
    const int r = j * 32 + srow_w + sr;
    laneB[j] = (o0 + r) * KTOT + ((slot ^ (r & 7)) << 3);
  }

  auto stage = [&](int buf, int q) {
    const int c0 = q * BK;
    if constexpr (CIN >= 64) {
      const int pbase = nei_sh[c0 >> CSH] * (NPT << CSH) + (c0 & (CIN - 1));
#pragma unroll
      for (int j = 0; j < BM / 32; ++j)
        gload_lds16(Xin + pbase + laneA[j], &smA[buf][(j * 32 + srow_w) * BK]);
    } else {
#pragma unroll
      for (int j = 0; j < BM / 32; ++j) {
        const int r = j * 32 + srow_w + sr;
        const int kk = c0 + swz[j];
        const int nbr = kk >> CSH;
        const int cc = kk & (CIN - 1);
        gload_lds16(Xin + ((nei_sh[nbr] * NPT + n0 + r) << CSH) + cc,
                    &smA[buf][(j * 32 + srow_w) * BK]);
      }
    }
#pragma unroll
    for (int j = 0; j < BN / 32; ++j)
      gload_lds16(Wb + laneB[j] + c0, &smB[buf][(j * 32 + srow_w) * BK]);
  };

  f32x4 acc[M_REP][N_REP] = {};

  stage(0, qb);
  asm volatile("s_waitcnt vmcnt(0)" ::: "memory");
  __builtin_amdgcn_s_barrier();

  int cur = 0;
#pragma unroll 1
  for (int q = qb; q < qe; ++q) {
    if (q + 1 < qe) stage(cur ^ 1, q + 1);
#pragma unroll
    for (int ks = 0; ks < 2; ++ks) {
      const int cb = ks * 4 + lkg;
      s16x8 bf[N_REP];
#pragma unroll
      for (int n = 0; n < N_REP; ++n) {
        const int r = wc * WN + n * 16 + lrow;
        bf[n] = *(const s16x8*)&smB[cur][r * BK + ((cb ^ (r & 7)) << 3)];
      }
#pragma unroll
      for (int m = 0; m < M_REP; ++m) {
        const int r = wr * 64 + m * 16 + lrow;
        s16x8 af = *(const s16x8*)&smA[cur][r * BK + ((cb ^ (r & 7)) << 3)];
#pragma unroll
        for (int n = 0; n < N_REP; ++n)
          acc[m][n] = __builtin_amdgcn_mfma_f32_16x16x32_bf16(af, bf[n], acc[m][n], 0, 0, 0);
      }
    }
    asm volatile("s_waitcnt vmcnt(0)" ::: "memory");
    __builtin_amdgcn_s_barrier();
    cur ^= 1;
  }

  float* eqp = (MODE == 2) ? Eq + (size_t)kp * GSZ * NPT * 64 : Eq;
#pragma unroll
  for (int m = 0; m < M_REP; ++m) {
#pragma unroll
    for (int n = 0; n < N_REP; ++n) {
      const int oc = o0 + wc * WN + n * 16 + lrow;
      float bv;
      if (MODE == 2)
        bv = (oc < OREAL && addf) ? bias[oc] : 0.f;
      else
        bv = bias[oc];
#pragma unroll
      for (int r = 0; r < 4; ++r) {
        const int row = n0 + wr * 64 + m * 16 + lkg * 4 + r;
        float v = acc[m][n][r] + bv;
        if (MODE == 0) {
          if (RELU) v = v > 0.f ? v : 0.f;
          Xout[((size_t)g * NPT + row) * OPAD + oc] = f2bf(v);
        } else if (MODE == 1) {
          const size_t ix = ((size_t)g * NPT + row) * OPAD + oc;
          Xout[ix] = f2bf(bf2f(Xout[ix]) + v);
        } else {
          const float add = (oc < OREAL && addf) ? feats[((size_t)row * 32 + oc) * GSZ + g] : 0.f;
          eqp[((size_t)g * NPT + row) * 64 + oc] = v + add;
        }
      }
    }
  }
}

// Eq4: 4 split-K partials [4][G][N][64] fp32 -> out: inv [N][32], eqv [N][32][G]
__global__ __launch_bounds__(256) void finalize_k(const float* __restrict__ Eq,
                                                  float* __restrict__ out) {
  const int n = blockIdx.x;
  const int t = threadIdx.x;
  const int c = t & 31;
  const int gs = t >> 5;
  constexpr size_t PART = (size_t)GSZ * NPT * 64;

  float invp = 0.f;
  for (int g = gs; g < GSZ; g += 8) {
    const size_t base = ((size_t)g * NPT + n) * 64 + c;
    float x = Eq[base] + Eq[PART + base] + Eq[2 * PART + base] + Eq[3 * PART + base];
    invp += x;
    float ss = x * x;
#pragma unroll
    for (int m = 16; m >= 1; m >>= 1) ss += __shfl_xor(ss, m, 64);
    float nrm = sqrtf(ss);
    nrm = nrm > 1e-4f ? nrm : 1e-4f;
    out[16384 + ((size_t)n * 32 + c) * GSZ + g] = x / nrm;
  }

  __shared__ float tmp[8][32];
  tmp[gs][c] = invp;
  __syncthreads();
  if (t < 32) {
    float s = 0.f;
#pragma unroll
    for (int i = 0; i < 8; ++i) s += tmp[i][t];
    s *= (1.f / 60.f);
    float ss = s * s;
#pragma unroll
    for (int m = 16; m >= 1; m >>= 1) ss += __shfl_xor(ss, m, 64);
    float nrm = sqrtf(ss);
    nrm = nrm > 1e-4f ? nrm : 1e-4f;
    out[(size_t)n * 32 + t] = s / nrm;
  }
}

extern "C" void kernel_launch(void* const* d_in, const int* in_sizes, int n_in,
                              void* d_out, int out_size, void* d_ws, size_t ws_size,
                              hipStream_t stream) {
  const float* feats = (const float*)d_in[0];
  const int* nei = (const int*)d_in[1];
  const float* W_in = (const float*)d_in[2];
  const float* b_in = (const float*)d_in[3];
  const float* W_r1 = (const float*)d_in[4];
  const float* b_r1 = (const float*)d_in[5];
  const float* W_r2 = (const float*)d_in[6];
  const float* b_r2 = (const float*)d_in[7];
  const float* W_out = (const float*)d_in[8];
  const float* b_out = (const float*)d_in[9];
  float* out = (float*)d_out;

  char* ws = (char*)d_ws;
  size_t off = 0;
  auto alloc = [&](size_t bytes) {
    void* p = ws + off;
    off += (bytes + 255) & ~(size_t)255;
    return p;
  };
  ushort* X0 = (ushort*)alloc((size_t)61 * NPT * 32 * 2);    // 2.0 MB
  ushort* H1 = (ushort*)alloc((size_t)GSZ * NPT * 256 * 2);  // 15.7 MB (h1 -> h2)
  ushort* R = (ushort*)alloc((size_t)GSZ * NPT * 512 * 2);   // 31.5 MB; Eq4 alias after L3
  ushort* Wb_in = (ushort*)alloc((size_t)256 * 448 * 2);
  ushort* Wb_r1 = (ushort*)alloc((size_t)512 * 3328 * 2);
  ushort* Wb_r2 = (ushort*)alloc((size_t)256 * 6656 * 2);
  ushort* Wb_out = (ushort*)alloc((size_t)64 * 3328 * 2);
  float* Eq4 = (float*)R;  // [4][G][N][64] fp32, reuses R (dead after L3)

  // merged prep: one launch
  constexpr int PREP_TOT = 256 * 448 + 512 * 3328 + 256 * 6656 + 64 * 3328 + 61 * NPT * 32;
  prep_all_k<<<dim3((PREP_TOT + 255) / 256), dim3(256), 0, stream>>>(
      W_in, W_r1, W_r2, W_out, feats, Wb_in, Wb_r1, Wb_r2, Wb_out, X0);

  // L1: 32 -> 256 (KTOT 448, 7 chunks), grid 480
  comb_gemm<32, 448, 256, 256, 128, 0, false, 1><<<dim3(2 * 4 * GSZ), dim3(256), 0, stream>>>(
      X0, Wb_in, b_in, nei, H1, nullptr, nullptr, 0, 7);
  // L2: 256 -> 512, relu; r3-exact, grid 960
  comb_gemm<256, 3328, 512, 512, 128, 0, true, 1><<<dim3(4 * 4 * GSZ), dim3(256), 0, stream>>>(
      H1, Wb_r1, b_r1, nei, R, nullptr, nullptr, 0, 52);
  // L3: 512 -> 256, h2 = h1 + comb(r); r3-exact, grid 480
  comb_gemm<512, 6656, 256, 256, 128, 1, false, 1><<<dim3(2 * 4 * GSZ), dim3(256), 0, stream>>>(
      R, Wb_r2, b_r2, nei, H1, nullptr, nullptr, 0, 104);
  // L4: 256 -> 32 (pad 64), split-K x4 in ONE dispatch, grid 960 -> Eq4 partials
  comb_gemm<256, 3328, 64, 32, 64, 2, false, 4><<<dim3(4 * 1 * 4 * GSZ), dim3(256), 0, stream>>>(
      H1, Wb_out, b_out, nei, nullptr, Eq4, feats, 0, 0);
  finalize_k<<<NPT, 256, 0, stream>>>(Eq4, out);
}

// Round 11
// 315.459 us; speedup vs baseline: 1.1452x; 1.0207x over previous
//
#include <hip/hip_runtime.h>
#include <stdint.h>

#define GSZ 60
#define KNB 13
#define NPT 512

typedef __attribute__((ext_vector_type(4))) float f32x4;
typedef __attribute__((ext_vector_type(8))) short s16x8;

__device__ __forceinline__ ushort f2bf(float f) {
  union { float f; unsigned u; } v; v.f = f;
  unsigned r = v.u + 0x7fffu + ((v.u >> 16) & 1u);
  return (ushort)(r >> 16);
}
__device__ __forceinline__ float bf2f(ushort h) {
  union { unsigned u; float f; } v; v.u = ((unsigned)h) << 16;
  return v.f;
}

// async global->LDS, 16B per lane; dst wave-uniform (HW adds lane*16)
__device__ __forceinline__ void gload_lds16(const void* gsrc, void* ldst) {
  __builtin_amdgcn_global_load_lds(
      (const __attribute__((address_space(1))) uint32_t*)gsrc,
      (__attribute__((address_space(3))) uint32_t*)ldst, 16, 0, 0);
}

// ---- merged prep: all weight transposes + feats pack in ONE launch ----
__global__ __launch_bounds__(256) void prep_all_k(
    const float* __restrict__ W_in, const float* __restrict__ W_r1,
    const float* __restrict__ W_r2, const float* __restrict__ W_out,
    const float* __restrict__ feats,
    ushort* __restrict__ Wb_in, ushort* __restrict__ Wb_r1,
    ushort* __restrict__ Wb_r2, ushort* __restrict__ Wb_out,
    ushort* __restrict__ X0) {
  constexpr int N0 = 256 * 448;
  constexpr int N1 = 512 * 3328;
  constexpr int N2 = 256 * 6656;
  constexpr int N3 = 64 * 3328;
  constexpr int N4 = 61 * NPT * 32;
  int idx = blockIdx.x * 256 + threadIdx.x;
  if (idx < N0) {
    int o = idx / 448, kk = idx - o * 448, k = kk / 32, c = kk - k * 32;
    Wb_in[idx] = (k < KNB) ? f2bf(W_in[(o * 32 + c) * KNB + k]) : (ushort)0;
    return;
  }
  idx -= N0;
  if (idx < N1) {
    int o = idx / 3328, kk = idx - o * 3328, k = kk / 256, c = kk - k * 256;
    Wb_r1[idx] = f2bf(W_r1[(o * 256 + c) * KNB + k]);
    return;
  }
  idx -= N1;
  if (idx < N2) {
    int o = idx / 6656, kk = idx - o * 6656, k = kk / 512, c = kk - k * 512;
    Wb_r2[idx] = f2bf(W_r2[(o * 512 + c) * KNB + k]);
    return;
  }
  idx -= N2;
  if (idx < N3) {
    int o = idx / 3328, kk = idx - o * 3328, k = kk / 256, c = kk - k * 256;
    Wb_out[idx] = (o < 32) ? f2bf(W_out[(o * 256 + c) * KNB + k]) : (ushort)0;
    return;
  }
  idx -= N3;
  if (idx < N4) {
    int c = idx & 31, t = idx >> 5, n = t % NPT, g = t / NPT;
    X0[idx] = (g < GSZ) ? f2bf(feats[(n * 32 + c) * GSZ + g]) : (ushort)0;
  }
}

// ---------------- pristine r3 kernel: 4-wave 128xBN BK=64 dbuf (L1, L2, L3) ----------------
// Compile-time chunk count QE (qb=0). MODE 0: bf16(acc+bias) (+RELU); MODE 1: += residual.
template <int CIN, int KTOT, int OPAD, int BN, int QE, int MODE, bool RELU>
__global__ __launch_bounds__(256) void comb_gemm(
    const ushort* __restrict__ Xin, const ushort* __restrict__ Wb,
    const float* __restrict__ bias, const int* __restrict__ nei,
    ushort* __restrict__ Xout) {
  constexpr int BM = 128;
  constexpr int BK = 64;
  constexpr int TO = OPAD / BN;
  constexpr int TN = NPT / BM;
  constexpr int WN = BN / 2;
  constexpr int N_REP = WN / 16;
  constexpr int M_REP = 4;
  constexpr int CSH = (CIN == 32) ? 5 : (CIN == 256) ? 8 : 9;
  static_assert(CIN == (1 << CSH), "CIN pow2");

  __shared__ ushort smA[2][BM * BK];
  __shared__ ushort smB[2][BN * BK];
  __shared__ int nei_sh[16];

  const int nwg = TO * TN * GSZ;
  const int cpx = nwg >> 3;
  const int bid = blockIdx.x;
  const int idx = (bid & 7) * cpx + (bid >> 3);
  const int g = idx / (TO * TN);
  const int rem = idx - g * (TO * TN);
  const int nt = rem / TO;
  const int ot = rem - nt * TO;
  const int n0 = nt * BM;
  const int o0 = ot * BN;

  const int t = threadIdx.x;
  if (t < 14) nei_sh[t] = (t < KNB) ? nei[g * KNB + t] : GSZ;
  __syncthreads();

  const int w = t >> 6;
  const int l = t & 63;
  const int lrow = l & 15;
  const int lkg = l >> 4;
  const int wr = w >> 1;
  const int wc = w & 1;
  const int srow_w = w * 8;
  const int sr = l >> 3;
  const int slot = l & 7;

  int laneA[BM / 32], laneB[BN / 32], swz[BM / 32];
#pragma unroll
  for (int j = 0; j < BM / 32; ++j) {
    const int r = j * 32 + srow_w + sr;
    swz[j] = (slot ^ (r & 7)) << 3;
    laneA[j] = ((n0 + r) << CSH) + swz[j];
  }
#pragma unroll
  for (int j = 0; j < BN / 32; ++j) {
    const int r = j * 32 + srow_w + sr;
    laneB[j] = (o0 + r) * KTOT + ((slot ^ (r & 7)) << 3);
  }

  auto stage = [&](int buf, int q) {
    const int c0 = q * BK;
    if constexpr (CIN >= 64) {
      const int pbase = nei_sh[c0 >> CSH] * (NPT << CSH) + (c0 & (CIN - 1));
#pragma unroll
      for (int j = 0; j < BM / 32; ++j)
        gload_lds16(Xin + pbase + laneA[j], &smA[buf][(j * 32 + srow_w) * BK]);
    } else {
#pragma unroll
      for (int j = 0; j < BM / 32; ++j) {
        const int r = j * 32 + srow_w + sr;
        const int kk = c0 + swz[j];
        const int nbr = kk >> CSH;
        const int cc = kk & (CIN - 1);
        gload_lds16(Xin + ((nei_sh[nbr] * NPT + n0 + r) << CSH) + cc,
                    &smA[buf][(j * 32 + srow_w) * BK]);
      }
    }
#pragma unroll
    for (int j = 0; j < BN / 32; ++j)
      gload_lds16(Wb + laneB[j] + c0, &smB[buf][(j * 32 + srow_w) * BK]);
  };

  f32x4 acc[M_REP][N_REP] = {};

  stage(0, 0);
  asm volatile("s_waitcnt vmcnt(0)" ::: "memory");
  __builtin_amdgcn_s_barrier();

  int cur = 0;
#pragma unroll 1
  for (int q = 0; q < QE; ++q) {
    if (q + 1 < QE) stage(cur ^ 1, q + 1);
#pragma unroll
    for (int ks = 0; ks < 2; ++ks) {
      const int cb = ks * 4 + lkg;
      s16x8 bf[N_REP];
#pragma unroll
      for (int n = 0; n < N_REP; ++n) {
        const int r = wc * WN + n * 16 + lrow;
        bf[n] = *(const s16x8*)&smB[cur][r * BK + ((cb ^ (r & 7)) << 3)];
      }
#pragma unroll
      for (int m = 0; m < M_REP; ++m) {
        const int r = wr * 64 + m * 16 + lrow;
        s16x8 af = *(const s16x8*)&smA[cur][r * BK + ((cb ^ (r & 7)) << 3)];
#pragma unroll
        for (int n = 0; n < N_REP; ++n)
          acc[m][n] = __builtin_amdgcn_mfma_f32_16x16x32_bf16(af, bf[n], acc[m][n], 0, 0, 0);
      }
    }
    asm volatile("s_waitcnt vmcnt(0)" ::: "memory");
    __builtin_amdgcn_s_barrier();
    cur ^= 1;
  }

#pragma unroll
  for (int m = 0; m < M_REP; ++m) {
#pragma unroll
    for (int n = 0; n < N_REP; ++n) {
      const int oc = o0 + wc * WN + n * 16 + lrow;
      const float bv = bias[oc];
#pragma unroll
      for (int r = 0; r < 4; ++r) {
        const int row = n0 + wr * 64 + m * 16 + lkg * 4 + r;
        float v = acc[m][n][r] + bv;
        if (MODE == 0) {
          if (RELU) v = v > 0.f ? v : 0.f;
          Xout[((size_t)g * NPT + row) * OPAD + oc] = f2bf(v);
        } else {  // MODE 1: residual accumulate
          const size_t ix = ((size_t)g * NPT + row) * OPAD + oc;
          Xout[ix] = f2bf(bf2f(Xout[ix]) + v);
        }
      }
    }
  }
}

// ---------------- dedicated L4 kernel: split-K x4, one dispatch, grid 960 ----------------
// CIN=256, KTOT=3328, OPAD=64 (OREAL=32), BN=64. Part kp does chunks [kp*13, kp*13+13);
// writes fp32 partial at Eq + kp*G*N*64; bias+feats added only in part 0.
__global__ __launch_bounds__(256) void comb_l4(
    const ushort* __restrict__ Xin, const ushort* __restrict__ Wb,
    const float* __restrict__ bias, const int* __restrict__ nei,
    float* __restrict__ Eq, const float* __restrict__ feats) {
  constexpr int CIN = 256, KTOT = 3328, OPAD = 64, OREAL = 32, BN = 64;
  constexpr int BM = 128, BK = 64, CSH = 8;
  constexpr int WN = BN / 2;      // 32
  constexpr int N_REP = WN / 16;  // 2
  constexpr int M_REP = 4;
  constexpr int TN = NPT / BM;    // 4

  __shared__ ushort smA[2][BM * BK];
  __shared__ ushort smB[2][BN * BK];
  __shared__ int nei_sh[16];

  constexpr int nparts = TN * GSZ;       // 240
  constexpr int nwg = nparts * 4;        // 960
  constexpr int cpx = nwg >> 3;
  const int bid = blockIdx.x;
  const int idx = (bid & 7) * cpx + (bid >> 3);
  const int kp = idx / nparts;
  const int sub = idx - kp * nparts;
  const int g = sub / TN;
  const int nt = sub - g * TN;
  const int n0 = nt * BM;
  const int qb = kp * 13, qe = qb + 13;
  const bool addf = (kp == 0);

  const int t = threadIdx.x;
  if (t < 14) nei_sh[t] = (t < KNB) ? nei[g * KNB + t] : GSZ;
  __syncthreads();

  const int w = t >> 6;
  const int l = t & 63;
  const int lrow = l & 15;
  const int lkg = l >> 4;
  const int wr = w >> 1;
  const int wc = w & 1;
  const int srow_w = w * 8;
  const int sr = l >> 3;
  const int slot = l & 7;

  int laneA[4], laneB[2];
#pragma unroll
  for (int j = 0; j < 4; ++j) {
    const int r = j * 32 + srow_w + sr;
    laneA[j] = ((n0 + r) << CSH) + ((slot ^ (r & 7)) << 3);
  }
#pragma unroll
  for (int j = 0; j < 2; ++j) {
    const int r = j * 32 + srow_w + sr;
    laneB[j] = r * KTOT + ((slot ^ (r & 7)) << 3);
  }

  auto stage = [&](int buf, int q) {
    const int c0 = q * BK;
    const int pbase = nei_sh[c0 >> CSH] * (NPT << CSH) + (c0 & (CIN - 1));
#pragma unroll
    for (int j = 0; j < 4; ++j)
      gload_lds16(Xin + pbase + laneA[j], &smA[buf][(j * 32 + srow_w) * BK]);
#pragma unroll
    for (int j = 0; j < 2; ++j)
      gload_lds16(Wb + laneB[j] + c0, &smB[buf][(j * 32 + srow_w) * BK]);
  };

  f32x4 acc[M_REP][N_REP] = {};

  stage(0, qb);
  asm volatile("s_waitcnt vmcnt(0)" ::: "memory");
  __builtin_amdgcn_s_barrier();

  int cur = 0;
#pragma unroll 1
  for (int q = qb; q < qe; ++q) {
    if (q + 1 < qe) stage(cur ^ 1, q + 1);
#pragma unroll
    for (int ks = 0; ks < 2; ++ks) {
      const int cb = ks * 4 + lkg;
      s16x8 bf[N_REP];
#pragma unroll
      for (int n = 0; n < N_REP; ++n) {
        const int r = wc * WN + n * 16 + lrow;
        bf[n] = *(const s16x8*)&smB[cur][r * BK + ((cb ^ (r & 7)) << 3)];
      }
#pragma unroll
      for (int m = 0; m < M_REP; ++m) {
        const int r = wr * 64 + m * 16 + lrow;
        s16x8 af = *(const s16x8*)&smA[cur][r * BK + ((cb ^ (r & 7)) << 3)];
#pragma unroll
        for (int n = 0; n < N_REP; ++n)
          acc[m][n] = __builtin_amdgcn_mfma_f32_16x16x32_bf16(af, bf[n], acc[m][n], 0, 0, 0);
      }
    }
    asm volatile("s_waitcnt vmcnt(0)" ::: "memory");
    __builtin_amdgcn_s_barrier();
    cur ^= 1;
  }

  float* eqp = Eq + (size_t)kp * GSZ * NPT * 64;
#pragma unroll
  for (int m = 0; m < M_REP; ++m) {
#pragma unroll
    for (int n = 0; n < N_REP; ++n) {
      const int oc = wc * WN + n * 16 + lrow;
      const float bv = (oc < OREAL && addf) ? bias[oc] : 0.f;
#pragma unroll
      for (int r = 0; r < 4; ++r) {
        const int row = n0 + wr * 64 + m * 16 + lkg * 4 + r;
        float v = acc[m][n][r] + bv;
        const float add = (oc < OREAL && addf) ? feats[((size_t)row * 32 + oc) * GSZ + g] : 0.f;
        eqp[((size_t)g * NPT + row) * 64 + oc] = v + add;
      }
    }
  }
}

// Eq4: 4 split-K partials [4][G][N][64] fp32 -> out: inv [N][32], eqv [N][32][G]
__global__ __launch_bounds__(256) void finalize_k(const float* __restrict__ Eq,
                                                  float* __restrict__ out) {
  const int n = blockIdx.x;
  const int t = threadIdx.x;
  const int c = t & 31;
  const int gs = t >> 5;
  constexpr size_t PART = (size_t)GSZ * NPT * 64;

  float invp = 0.f;
  for (int g = gs; g < GSZ; g += 8) {
    const size_t base = ((size_t)g * NPT + n) * 64 + c;
    float x = Eq[base] + Eq[PART + base] + Eq[2 * PART + base] + Eq[3 * PART + base];
    invp += x;
    float ss = x * x;
#pragma unroll
    for (int m = 16; m >= 1; m >>= 1) ss += __shfl_xor(ss, m, 64);
    float nrm = sqrtf(ss);
    nrm = nrm > 1e-4f ? nrm : 1e-4f;
    out[16384 + ((size_t)n * 32 + c) * GSZ + g] = x / nrm;
  }

  __shared__ float tmp[8][32];
  tmp[gs][c] = invp;
  __syncthreads();
  if (t < 32) {
    float s = 0.f;
#pragma unroll
    for (int i = 0; i < 8; ++i) s += tmp[i][t];
    s *= (1.f / 60.f);
    float ss = s * s;
#pragma unroll
    for (int m = 16; m >= 1; m >>= 1) ss += __shfl_xor(ss, m, 64);
    float nrm = sqrtf(ss);
    nrm = nrm > 1e-4f ? nrm : 1e-4f;
    out[(size_t)n * 32 + t] = s / nrm;
  }
}

extern "C" void kernel_launch(void* const* d_in, const int* in_sizes, int n_in,
                              void* d_out, int out_size, void* d_ws, size_t ws_size,
                              hipStream_t stream) {
  const float* feats = (const float*)d_in[0];
  const int* nei = (const int*)d_in[1];
  const float* W_in = (const float*)d_in[2];
  const float* b_in = (const float*)d_in[3];
  const float* W_r1 = (const float*)d_in[4];
  const float* b_r1 = (const float*)d_in[5];
  const float* W_r2 = (const float*)d_in[6];
  const float* b_r2 = (const float*)d_in[7];
  const float* W_out = (const float*)d_in[8];
  const float* b_out = (const float*)d_in[9];
  float* out = (float*)d_out;

  char* ws = (char*)d_ws;
  size_t off = 0;
  auto alloc = [&](size_t bytes) {
    void* p = ws + off;
    off += (bytes + 255) & ~(size_t)255;
    return p;
  };
  ushort* X0 = (ushort*)alloc((size_t)61 * NPT * 32 * 2);    // 2.0 MB
  ushort* H1 = (ushort*)alloc((size_t)GSZ * NPT * 256 * 2);  // 15.7 MB (h1 -> h2)
  ushort* R = (ushort*)alloc((size_t)GSZ * NPT * 512 * 2);   // 31.5 MB; Eq4 alias after L3
  ushort* Wb_in = (ushort*)alloc((size_t)256 * 448 * 2);
  ushort* Wb_r1 = (ushort*)alloc((size_t)512 * 3328 * 2);
  ushort* Wb_r2 = (ushort*)alloc((size_t)256 * 6656 * 2);
  ushort* Wb_out = (ushort*)alloc((size_t)64 * 3328 * 2);
  float* Eq4 = (float*)R;  // [4][G][N][64] fp32, reuses R (dead after L3)

  // merged prep: one launch
  constexpr int PREP_TOT = 256 * 448 + 512 * 3328 + 256 * 6656 + 64 * 3328 + 61 * NPT * 32;
  prep_all_k<<<dim3((PREP_TOT + 255) / 256), dim3(256), 0, stream>>>(
      W_in, W_r1, W_r2, W_out, feats, Wb_in, Wb_r1, Wb_r2, Wb_out, X0);

  // L1: 32 -> 256 (KTOT 448, 7 chunks), grid 480
  comb_gemm<32, 448, 256, 128, 7, 0, false><<<dim3(2 * 4 * GSZ), dim3(256), 0, stream>>>(
      X0, Wb_in, b_in, nei, H1);
  // L2: 256 -> 512, relu; pristine r3, compile-time 52 chunks, grid 960
  comb_gemm<256, 3328, 512, 128, 52, 0, true><<<dim3(4 * 4 * GSZ), dim3(256), 0, stream>>>(
      H1, Wb_r1, b_r1, nei, R);
  // L3: 512 -> 256, h2 = h1 + comb(r); pristine r3, compile-time 104 chunks, grid 480
  comb_gemm<512, 6656, 256, 128, 104, 1, false><<<dim3(2 * 4 * GSZ), dim3(256), 0, stream>>>(
      R, Wb_r2, b_r2, nei, H1);
  // L4: 256 -> 32 (pad 64), split-K x4 in ONE dispatch, grid 960 -> Eq4 partials
  comb_l4<<<dim3(960), dim3(256), 0, stream>>>(H1, Wb_out, b_out, nei, Eq4, feats);
  finalize_k<<<NPT, 256, 0, stream>>>(Eq4, out);
}